// Round 9
// baseline (199.187 us; speedup 1.0000x reference)
//
#include <hip/hip_runtime.h>
#include <hip/hip_bf16.h>

typedef __bf16 bf16;
typedef __attribute__((ext_vector_type(8))) __bf16 bf16x8;
typedef __attribute__((ext_vector_type(4))) __bf16 bf16x4;
typedef __attribute__((ext_vector_type(16))) float f32x16;

#define N_ROWS 16384
#define DIM 256
#define NT 128
#define LSTRIP 8
#define NSTRIPS 1088     /* sum_{it} ceil((128-it)/8) */
#define SQK1 4.53981608f /* sqrt(1/(0.07*ln2)): A pre-scaled so e^{z} = 2^{dot'} */
#define LN2F 0.69314718056f

#define WS_T_OFF (N_ROWS * DIM * 2)
#define WS_D_OFF (WS_T_OFF + N_ROWS * 4)

#define GLOAD_LDS(g, l)                                        \
    __builtin_amdgcn_global_load_lds(                          \
        (const __attribute__((address_space(1))) void*)(g),    \
        (__attribute__((address_space(3))) void*)(l), 16, 0, 0)

// Kernel 1: L2-normalize rows, scale by SQK1, emit bf16 A' to ws. Zeros T[]
// and d_out. Dg[row] = s2' = sum(bf16(SQK1*a)^2) = the MFMA diagonal, so the
// diagonal's bf16 rounding error cancels: loss_i = ln2*(log2(T'_i) - s2'_i).
__global__ void __launch_bounds__(256) normalize_kernel(const float* __restrict__ in,
                                                        bf16* __restrict__ out,
                                                        float* __restrict__ Tg,
                                                        float* __restrict__ Dg,
                                                        float* __restrict__ loss_out) {
    if (blockIdx.x == 0 && threadIdx.x == 0) loss_out[0] = 0.0f;
    if (blockIdx.x < 64) Tg[blockIdx.x * 256 + threadIdx.x] = 0.0f;

    const int row  = blockIdx.x * 4 + (threadIdx.x >> 6);
    const int lane = threadIdx.x & 63;
    const float4* rp = (const float4*)(in + (size_t)row * DIM);
    float4 v = rp[lane];
    float ss = v.x * v.x + v.y * v.y + v.z * v.z + v.w * v.w;
#pragma unroll
    for (int m = 1; m < 64; m <<= 1) ss += __shfl_xor(ss, m, 64);
    float inv = SQK1 / fmaxf(sqrtf(ss), 1e-12f);
    bf16x4 o;
    o[0] = (bf16)(v.x * inv);
    o[1] = (bf16)(v.y * inv);
    o[2] = (bf16)(v.z * inv);
    o[3] = (bf16)(v.w * inv);
    *(bf16x4*)(out + (size_t)row * DIM + lane * 4) = o;

    float f0 = (float)o[0], f1 = (float)o[1], f2 = (float)o[2], f3 = (float)o[3];
    float s2 = f0 * f0 + f1 * f1 + f2 * f2 + f3 * f3;
#pragma unroll
    for (int m = 1; m < 64; m <<= 1) s2 += __shfl_xor(s2, m, 64);
    if (lane == 0) Dg[row] = s2;
}

// Tree-reduce 16 floats across the 32 `lo` lanes; every lane ends with the
// full sum for register index r = (lo>>1)&15. (Correctness-proven R4-R8.)
#define TREE16(R, out)                                                     \
    do {                                                                   \
        float w8[8], w4[4], w2[2], w1, g_;                                 \
        _Pragma("unroll") for (int i_ = 0; i_ < 8; ++i_) {                 \
            g_ = (lo & 16) ? R[i_] : R[i_ + 8];                            \
            w8[i_] = ((lo & 16) ? R[i_ + 8] : R[i_]) + __shfl_xor(g_, 16); \
        }                                                                  \
        _Pragma("unroll") for (int i_ = 0; i_ < 4; ++i_) {                 \
            g_ = (lo & 8) ? w8[i_] : w8[i_ + 4];                           \
            w4[i_] = ((lo & 8) ? w8[i_ + 4] : w8[i_]) + __shfl_xor(g_, 8); \
        }                                                                  \
        _Pragma("unroll") for (int i_ = 0; i_ < 2; ++i_) {                 \
            g_ = (lo & 4) ? w4[i_] : w4[i_ + 2];                           \
            w2[i_] = ((lo & 4) ? w4[i_ + 2] : w4[i_]) + __shfl_xor(g_, 4); \
        }                                                                  \
        g_ = (lo & 2) ? w2[0] : w2[1];                                     \
        w1 = ((lo & 2) ? w2[1] : w2[0]) + __shfl_xor(g_, 2);               \
        out = w1 + __shfl_xor(w1, 1);                                      \
    } while (0)

// Kernel 2: symmetric A'A'^T + softmax denominator.
// 512 thr = 8 waves = 2 row-groups x 4 col-groups per 128x128 tile.
// af (64 rows x K=256) persistent in AGPRs. B tile (64 KB) staged via
// global_load_lds w=16 into TWO DISTINCT LDS arrays (Bs0/Bs1) with the jt
// loop unrolled x2 so buffer binding is STATIC -> LLVM's waitcnt pass can
// disambiguate reads of one buffer from in-flight DMAs into the other and
// emits a precise (non-zero) vmcnt wait; the prefetch survives the barrier.
// No global atomics inside the loop: per-tile col sums accumulate in LDS
// (CsAcc) and flush once at strip end.
__global__ void __launch_bounds__(512, 1)
loss_kernel(const bf16* __restrict__ A, float* __restrict__ Tg) {
    __shared__ bf16 Bs0[128 * DIM];        // 64 KB
    __shared__ bf16 Bs1[128 * DIM];        // 64 KB
    __shared__ float CsAcc[2][LSTRIP][128];  // 8 KB

    const int tid = threadIdx.x;
    const int w  = tid >> 6;
    const int l  = tid & 63;
    const int lo = l & 31, hi = l >> 5;
    const int rg = w >> 2;   // row-group: rows rg*64..+63
    const int cg = w & 3;    // col-group: cols cg*32..+31

    // strip decode
    int it = 0, rem = blockIdx.x;
    for (;;) {
        int nch = (NT - it + LSTRIP - 1) / LSTRIP;
        if (rem < nch) break;
        rem -= nch;
        ++it;
    }
    const int jt0 = it + rem * LSTRIP;
    const int jt1 = (jt0 + LSTRIP < NT) ? (jt0 + LSTRIP) : NT;

    const int arow = rg * 64;

    // persistent A fragments (A-operand: m = lo, k = hi*8 + j); static unroll
    bf16x8 af0[16], af1[16];
    {
        const bf16* ap0 = A + (size_t)(it * 128 + arow + lo) * DIM + hi * 8;
#pragma unroll
        for (int k = 0; k < 16; ++k) {
            af0[k] = *(const volatile bf16x8*)(ap0 + k * 16);
            af1[k] = *(const volatile bf16x8*)(ap0 + 32 * DIM + k * 16);
        }
    }

    float s0[16], s1[16];
#pragma unroll
    for (int r = 0; r < 16; ++r) { s0[r] = 0.f; s1[r] = 0.f; }

    // DMA lane constants. Wave w stages tile rows w*16..+15 in 8 instrs
    // (2 rows each). Lane: rl = l>>5 (row in pair), s = l&31 (LDS slot).
    // Slot s of row r holds global chunk c = (s&24)|((s&7)^(r&7)).
    const int s_dma = l & 31;
    const int rl    = l >> 5;
    int vo[4];
#pragma unroll
    for (int j = 0; j < 4; ++j) {
        const int c = (s_dma & 24) | ((s_dma & 7) ^ ((j * 2 + rl) & 7));
        vo[j] = rl * DIM + c * 8;
    }

    // fragment-read constants: row = cg*32+lo; chunk cc at slot
    // (cc&24)|((cc&7)^(lo&7))
    const int rbase = (cg * 32 + lo) * DIM;
    const int mx7 = lo & 7;

#define ISSUE(jtn, BUF)                                                      \
    do {                                                                     \
        const bf16* tb_ = A + (size_t)(jtn) * 128 * DIM + (w * 16) * DIM;    \
        bf16* lb_ = &BUF[(w * 16) * DIM];                                    \
        _Pragma("unroll") for (int q_ = 0; q_ < 8; ++q_) {                   \
            GLOAD_LDS(tb_ + (q_ * 2) * DIM + vo[q_ & 3],                     \
                      lb_ + (q_ * 2) * DIM);                                 \
        }                                                                    \
    } while (0)

    // One tile: barrier (BW free) -> prefetch jt+1 into BW -> wait this
    // tile's DMA -> barrier (BR ready) -> 32 MFMA from BR -> epilogue.
#define TILE_BODY(BR, BW, jt, t)                                             \
    do {                                                                     \
        asm volatile("s_barrier" ::: "memory");                              \
        if ((jt) + 1 < jt1) {                                                \
            ISSUE((jt) + 1, BW);                                             \
            asm volatile("s_waitcnt vmcnt(8)" ::: "memory");                 \
        } else {                                                             \
            asm volatile("s_waitcnt vmcnt(0)" ::: "memory");                 \
        }                                                                    \
        asm volatile("s_barrier" ::: "memory");                              \
        f32x16 c0, c1;                                                       \
        _Pragma("unroll") for (int r_ = 0; r_ < 16; ++r_) {                  \
            c0[r_] = 0.f; c1[r_] = 0.f;                                      \
        }                                                                    \
        _Pragma("unroll") for (int k_ = 0; k_ < 16; ++k_) {                  \
            const int cc_ = k_ * 2 + hi;                                     \
            const int slot_ = (cc_ & 24) | ((cc_ & 7) ^ mx7);                \
            bf16x8 b_ = *(const bf16x8*)&BR[rbase + slot_ * 8];              \
            c0 = __builtin_amdgcn_mfma_f32_32x32x16_bf16(af0[k_], b_, c0, 0, 0, 0); \
            c1 = __builtin_amdgcn_mfma_f32_32x32x16_bf16(af1[k_], b_, c1, 0, 0, 0); \
        }                                                                    \
        float cs_ = 0.f;                                                     \
        _Pragma("unroll") for (int r_ = 0; r_ < 16; ++r_) {                  \
            float e0_ = __builtin_amdgcn_exp2f(c0[r_]);                      \
            float e1_ = __builtin_amdgcn_exp2f(c1[r_]);                      \
            s0[r_] += e0_;                                                   \
            s1[r_] += e1_;                                                   \
            cs_ += e0_ + e1_;                                                \
        }                                                                    \
        cs_ += __shfl_xor(cs_, 32);                                          \
        if (hi == 0) CsAcc[rg][t][cg * 32 + lo] = cs_;                       \
    } while (0)

    ISSUE(jt0, Bs0);
    int jt = jt0;
    while (jt < jt1) {
        TILE_BODY(Bs0, Bs1, jt, jt - jt0);
        ++jt;
        if (jt >= jt1) break;
        TILE_BODY(Bs1, Bs0, jt, jt - jt0);
        ++jt;
    }

    // strip end: row sums. C/D row = (r&3)+8*(r>>2)+4*hi; even lanes own c0
    // rows, odd own c1 rows (+32).
    float t0, t1;
    TREE16(s0, t0);
    TREE16(s1, t1);
    const int r = (lo >> 1) & 15;
    const int rowoff = (r & 3) + 8 * (r >> 2) + 4 * hi;
    atomicAdd(&Tg[it * 128 + arow + ((l & 1) ? 32 : 0) + rowoff], (l & 1) ? t1 : t0);

    // col-sum flush: one pass over CsAcc, global atomics outside the pipeline
    __syncthreads();
    const int nt_strip = jt1 - jt0;
    for (int i = tid; i < nt_strip * 128; i += 512) {
        const int t = i >> 7, col = i & 127;
        if (jt0 + t != it) {
            atomicAdd(&Tg[(jt0 + t) * 128 + col],
                      CsAcc[0][t][col] + CsAcc[1][t][col]);
        }
    }
#undef ISSUE
#undef TILE_BODY
}

// Kernel 3: loss_i = ln2*(log2(T'_i) - s2'_i), mean over rows.
__global__ void __launch_bounds__(256) final_kernel(const float* __restrict__ Tg,
                                                    const float* __restrict__ Dg,
                                                    float* __restrict__ out) {
    __shared__ float red[4];
    const int i = blockIdx.x * 256 + threadIdx.x;
    float c = LN2F * (__log2f(Tg[i]) - Dg[i]) * (1.0f / (float)N_ROWS);
#pragma unroll
    for (int m = 1; m < 64; m <<= 1) c += __shfl_xor(c, m, 64);
    if ((threadIdx.x & 63) == 0) red[threadIdx.x >> 6] = c;
    __syncthreads();
    if (threadIdx.x == 0)
        atomicAdd(out, red[0] + red[1] + red[2] + red[3]);
}

extern "C" void kernel_launch(void* const* d_in, const int* in_sizes, int n_in,
                              void* d_out, int out_size, void* d_ws, size_t ws_size,
                              hipStream_t stream) {
    const float* emb = (const float*)d_in[0];
    float* out = (float*)d_out;
    bf16* Abf = (bf16*)d_ws;
    float* Tg = (float*)((char*)d_ws + WS_T_OFF);
    float* Dg = (float*)((char*)d_ws + WS_D_OFF);

    hipLaunchKernelGGL(normalize_kernel, dim3(N_ROWS / 4), dim3(256), 0, stream,
                       emb, Abf, Tg, Dg, out);
    hipLaunchKernelGGL(loss_kernel, dim3(NSTRIPS), dim3(512), 0, stream,
                       Abf, Tg);
    hipLaunchKernelGGL(final_kernel, dim3(N_ROWS / 256), dim3(256), 0, stream,
                       Tg, Dg, out);
}

// Round 10
// 173.990 us; speedup vs baseline: 1.1448x; 1.1448x over previous
//
#include <hip/hip_runtime.h>
#include <hip/hip_bf16.h>

typedef __bf16 bf16;
typedef __attribute__((ext_vector_type(8))) __bf16 bf16x8;
typedef __attribute__((ext_vector_type(4))) __bf16 bf16x4;
typedef __attribute__((ext_vector_type(16))) float f32x16;

#define N_ROWS 16384
#define DIM 256
#define NT 128            /* 128-row tiles */
#define NJC 256           /* 64-col tiles */
#define LSTRIP 8
#define NSTRIPS 2112      /* sum_{it} ceil((256-2it)/8) */
#define SQK1 4.53981608f  /* sqrt(1/(0.07*ln2)): A pre-scaled so e^{z} = 2^{dot'} */
#define LN2F 0.69314718056f

#define WS_T_OFF (N_ROWS * DIM * 2)
#define WS_D_OFF (WS_T_OFF + N_ROWS * 4)

#define GLOAD_LDS(g, l)                                        \
    __builtin_amdgcn_global_load_lds(                          \
        (const __attribute__((address_space(1))) void*)(g),    \
        (__attribute__((address_space(3))) void*)(l), 16, 0, 0)

// Kernel 1: L2-normalize rows, scale by SQK1, emit bf16 A' to ws. Zeros T[]
// and d_out. Dg[row] = s2' = sum(bf16(SQK1*a)^2) = the MFMA diagonal, so the
// diagonal's bf16 rounding error cancels: loss_i = ln2*(log2(T'_i) - s2'_i).
__global__ void __launch_bounds__(256) normalize_kernel(const float* __restrict__ in,
                                                        bf16* __restrict__ out,
                                                        float* __restrict__ Tg,
                                                        float* __restrict__ Dg,
                                                        float* __restrict__ loss_out) {
    if (blockIdx.x == 0 && threadIdx.x == 0) loss_out[0] = 0.0f;
    if (blockIdx.x < 64) Tg[blockIdx.x * 256 + threadIdx.x] = 0.0f;

    const int row  = blockIdx.x * 4 + (threadIdx.x >> 6);
    const int lane = threadIdx.x & 63;
    const float4* rp = (const float4*)(in + (size_t)row * DIM);
    float4 v = rp[lane];
    float ss = v.x * v.x + v.y * v.y + v.z * v.z + v.w * v.w;
#pragma unroll
    for (int m = 1; m < 64; m <<= 1) ss += __shfl_xor(ss, m, 64);
    float inv = SQK1 / fmaxf(sqrtf(ss), 1e-12f);
    bf16x4 o;
    o[0] = (bf16)(v.x * inv);
    o[1] = (bf16)(v.y * inv);
    o[2] = (bf16)(v.z * inv);
    o[3] = (bf16)(v.w * inv);
    *(bf16x4*)(out + (size_t)row * DIM + lane * 4) = o;

    float f0 = (float)o[0], f1 = (float)o[1], f2 = (float)o[2], f3 = (float)o[3];
    float s2 = f0 * f0 + f1 * f1 + f2 * f2 + f3 * f3;
#pragma unroll
    for (int m = 1; m < 64; m <<= 1) s2 += __shfl_xor(s2, m, 64);
    if (lane == 0) Dg[row] = s2;
}

// Tree-reduce 16 floats across the 32 `lo` lanes; every lane ends with the
// full sum for register index r = (lo>>1)&15. (Correctness-proven R4-R9.)
#define TREE16(R, out)                                                     \
    do {                                                                   \
        float w8[8], w4[4], w2[2], w1, g_;                                 \
        _Pragma("unroll") for (int i_ = 0; i_ < 8; ++i_) {                 \
            g_ = (lo & 16) ? R[i_] : R[i_ + 8];                            \
            w8[i_] = ((lo & 16) ? R[i_ + 8] : R[i_]) + __shfl_xor(g_, 16); \
        }                                                                  \
        _Pragma("unroll") for (int i_ = 0; i_ < 4; ++i_) {                 \
            g_ = (lo & 8) ? w8[i_] : w8[i_ + 4];                           \
            w4[i_] = ((lo & 8) ? w8[i_ + 4] : w8[i_]) + __shfl_xor(g_, 8); \
        }                                                                  \
        _Pragma("unroll") for (int i_ = 0; i_ < 2; ++i_) {                 \
            g_ = (lo & 4) ? w4[i_] : w4[i_ + 2];                           \
            w2[i_] = ((lo & 4) ? w4[i_ + 2] : w4[i_]) + __shfl_xor(g_, 4); \
        }                                                                  \
        g_ = (lo & 2) ? w2[0] : w2[1];                                     \
        w1 = ((lo & 2) ? w2[1] : w2[0]) + __shfl_xor(g_, 2);               \
        out = w1 + __shfl_xor(w1, 1);                                      \
    } while (0)

// Kernel 2: symmetric A'A'^T + softmax denominator.
// 256 thr = 4 waves = 2 row-groups x 2 col-groups per 128x64 tile.
// LDS = 2 x 32 KB B buffers + 4 KB CsAcc = 68 KB -> TWO independent
// blocks/CU (the R8/R9 structure's 139 KB forced 1 block/CU: every stall
// had no other wave on the CU to hide it — all waves shared one barrier).
// af (64 rows x K=256) persistent in AGPRs (volatile, static indexing).
// B tile (64 cols x K=256 = 32 KB) staged via global_load_lds w=16 with
// XOR chunk-swizzle on the GLOBAL source (LDS dest = uniform base+lane*16).
// Pipeline: raw s_barrier + s_waitcnt vmcnt(8) (R5/R8/R9-validated).
__global__ void __launch_bounds__(256, 2)
loss_kernel(const bf16* __restrict__ A, float* __restrict__ Tg) {
    __shared__ bf16 Bs0[64 * DIM];          // 32 KB
    __shared__ bf16 Bs1[64 * DIM];          // 32 KB
    __shared__ float CsAcc[2][LSTRIP][64];  // 4 KB

    const int tid = threadIdx.x;
    const int w  = tid >> 6;
    const int l  = tid & 63;
    const int lo = l & 31, hi = l >> 5;
    const int rg = w >> 1;   // row-group: rows rg*64..+63 (of the 128-row tile)
    const int cg = w & 1;    // col-group: cols cg*32..+31 (of the 64-col tile)

    // strip decode: (it, chunk of up to 8 col-tiles starting at jc0 >= 2*it)
    int it = 0, rem = blockIdx.x;
    for (;;) {
        int nch = (NJC - 2 * it + LSTRIP - 1) >> 3;
        if (rem < nch) break;
        rem -= nch;
        ++it;
    }
    const int jc0 = 2 * it + rem * LSTRIP;
    const int jc1 = (jc0 + LSTRIP < NJC) ? (jc0 + LSTRIP) : NJC;

    const int arow = rg * 64;

    // persistent A fragments (A-operand: m = lo, k = hi*8 + j); static unroll
    bf16x8 af0[16], af1[16];
    {
        const bf16* ap0 = A + (size_t)(it * 128 + arow + lo) * DIM + hi * 8;
#pragma unroll
        for (int k = 0; k < 16; ++k) {
            af0[k] = *(const volatile bf16x8*)(ap0 + k * 16);
            af1[k] = *(const volatile bf16x8*)(ap0 + 32 * DIM + k * 16);
        }
    }

    float s0[16], s1[16];
#pragma unroll
    for (int r = 0; r < 16; ++r) { s0[r] = 0.f; s1[r] = 0.f; }

    // DMA lane constants. Wave w stages B-tile rows w*16..+15 (cols of C) in
    // 8 instrs (2 rows each). Lane: rl = l>>5 (row in pair), s = l&31 (slot).
    // Slot s of row r holds global chunk c = (s&24)|((s&7)^(r&7)).
    const int s_dma = l & 31;
    const int rl    = l >> 5;
    int vo[4];
#pragma unroll
    for (int j = 0; j < 4; ++j) {
        const int c = (s_dma & 24) | ((s_dma & 7) ^ ((j * 2 + rl) & 7));
        vo[j] = rl * DIM + c * 8;
    }

    // fragment-read constants: B row = cg*32+lo; chunk cc at slot
    // (cc&24)|((cc&7)^(lo&7))
    const int rbase = (cg * 32 + lo) * DIM;
    const int mx7 = lo & 7;

#define ISSUE(jcn, BUF)                                                      \
    do {                                                                     \
        const bf16* tb_ = A + (size_t)((jcn) * 64 + w * 16) * DIM;           \
        bf16* lb_ = &BUF[(w * 16) * DIM];                                    \
        _Pragma("unroll") for (int q_ = 0; q_ < 8; ++q_) {                   \
            GLOAD_LDS(tb_ + (q_ * 2) * DIM + vo[q_ & 3],                     \
                      lb_ + (q_ * 2) * DIM);                                 \
        }                                                                    \
    } while (0)

#define TILE_BODY(BR, BW, jc, t)                                             \
    do {                                                                     \
        asm volatile("s_barrier" ::: "memory");                              \
        if ((jc) + 1 < jc1) {                                                \
            ISSUE((jc) + 1, BW);                                             \
            asm volatile("s_waitcnt vmcnt(8)" ::: "memory");                 \
        } else {                                                             \
            asm volatile("s_waitcnt vmcnt(0)" ::: "memory");                 \
        }                                                                    \
        asm volatile("s_barrier" ::: "memory");                              \
        f32x16 c0, c1;                                                       \
        _Pragma("unroll") for (int r_ = 0; r_ < 16; ++r_) {                  \
            c0[r_] = 0.f; c1[r_] = 0.f;                                      \
        }                                                                    \
        _Pragma("unroll") for (int k_ = 0; k_ < 16; ++k_) {                  \
            const int cc_ = k_ * 2 + hi;                                     \
            const int slot_ = (cc_ & 24) | ((cc_ & 7) ^ mx7);                \
            bf16x8 b_ = *(const bf16x8*)&BR[rbase + slot_ * 8];              \
            c0 = __builtin_amdgcn_mfma_f32_32x32x16_bf16(af0[k_], b_, c0, 0, 0, 0); \
            c1 = __builtin_amdgcn_mfma_f32_32x32x16_bf16(af1[k_], b_, c1, 0, 0, 0); \
        }                                                                    \
        float cs_ = 0.f;                                                     \
        _Pragma("unroll") for (int r_ = 0; r_ < 16; ++r_) {                  \
            float e0_ = __builtin_amdgcn_exp2f(c0[r_]);                      \
            float e1_ = __builtin_amdgcn_exp2f(c1[r_]);                      \
            s0[r_] += e0_;                                                   \
            s1[r_] += e1_;                                                   \
            cs_ += e0_ + e1_;                                                \
        }                                                                    \
        cs_ += __shfl_xor(cs_, 32);                                          \
        if (hi == 0) CsAcc[rg][t][cg * 32 + lo] = cs_;                       \
    } while (0)

    ISSUE(jc0, Bs0);
    int jc = jc0;
    while (jc < jc1) {
        TILE_BODY(Bs0, Bs1, jc, jc - jc0);
        ++jc;
        if (jc >= jc1) break;
        TILE_BODY(Bs1, Bs0, jc, jc - jc0);
        ++jc;
    }

    // strip end: row sums. C/D row = (r&3)+8*(r>>2)+4*hi; even lanes own c0
    // rows, odd own c1 rows (+32).
    float t0, t1;
    TREE16(s0, t0);
    TREE16(s1, t1);
    const int r = (lo >> 1) & 15;
    const int rowoff = (r & 3) + 8 * (r >> 2) + 4 * hi;
    atomicAdd(&Tg[it * 128 + arow + ((l & 1) ? 32 : 0) + rowoff], (l & 1) ? t1 : t0);

    // col-sum flush (skip the diagonal 128x128 block: jc>>1 == it — its
    // entries are fully covered by row sums).
    __syncthreads();
    const int nt_strip = jc1 - jc0;
    for (int i = tid; i < nt_strip * 64; i += 256) {
        const int t = i >> 6, col = i & 63;
        if (((jc0 + t) >> 1) != it) {
            atomicAdd(&Tg[(jc0 + t) * 64 + col],
                      CsAcc[0][t][col] + CsAcc[1][t][col]);
        }
    }
#undef ISSUE
#undef TILE_BODY
}

// Kernel 3: loss_i = ln2*(log2(T'_i) - s2'_i), mean over rows.
__global__ void __launch_bounds__(256) final_kernel(const float* __restrict__ Tg,
                                                    const float* __restrict__ Dg,
                                                    float* __restrict__ out) {
    __shared__ float red[4];
    const int i = blockIdx.x * 256 + threadIdx.x;
    float c = LN2F * (__log2f(Tg[i]) - Dg[i]) * (1.0f / (float)N_ROWS);
#pragma unroll
    for (int m = 1; m < 64; m <<= 1) c += __shfl_xor(c, m, 64);
    if ((threadIdx.x & 63) == 0) red[threadIdx.x >> 6] = c;
    __syncthreads();
    if (threadIdx.x == 0)
        atomicAdd(out, red[0] + red[1] + red[2] + red[3]);
}

extern "C" void kernel_launch(void* const* d_in, const int* in_sizes, int n_in,
                              void* d_out, int out_size, void* d_ws, size_t ws_size,
                              hipStream_t stream) {
    const float* emb = (const float*)d_in[0];
    float* out = (float*)d_out;
    bf16* Abf = (bf16*)d_ws;
    float* Tg = (float*)((char*)d_ws + WS_T_OFF);
    float* Dg = (float*)((char*)d_ws + WS_D_OFF);

    hipLaunchKernelGGL(normalize_kernel, dim3(N_ROWS / 4), dim3(256), 0, stream,
                       emb, Abf, Tg, Dg, out);
    hipLaunchKernelGGL(loss_kernel, dim3(NSTRIPS), dim3(256), 0, stream,
                       Abf, Tg);
    hipLaunchKernelGGL(final_kernel, dim3(N_ROWS / 256), dim3(256), 0, stream,
                       Tg, Dg, out);
}

// Round 11
// 167.691 us; speedup vs baseline: 1.1878x; 1.0376x over previous
//
#include <hip/hip_runtime.h>
#include <hip/hip_bf16.h>

typedef __bf16 bf16;
typedef __attribute__((ext_vector_type(8))) __bf16 bf16x8;
typedef __attribute__((ext_vector_type(4))) __bf16 bf16x4;
typedef __attribute__((ext_vector_type(16))) float f32x16;

#define N_ROWS 16384
#define DIM 256
#define NT 128            /* 128-row tiles */
#define NJC 256           /* 64-col tiles */
#define LSTRIP 8
#define NSTRIPS 2112      /* sum_{it} ceil((256-2it)/8) */
#define SQK1 4.53981608f  /* sqrt(1/(0.07*ln2)): A pre-scaled so e^{z} = 2^{dot'} */
#define LN2F 0.69314718056f

#define WS_T_OFF (N_ROWS * DIM * 2)
#define WS_D_OFF (WS_T_OFF + N_ROWS * 4)

#define GLOAD_LDS(g, l)                                        \
    __builtin_amdgcn_global_load_lds(                          \
        (const __attribute__((address_space(1))) void*)(g),    \
        (__attribute__((address_space(3))) void*)(l), 16, 0, 0)

// Kernel 1: L2-normalize rows, scale by SQK1, emit bf16 A' to ws. Zeros T[]
// and d_out. Dg[row] = s2' = sum(bf16(SQK1*a)^2) = the MFMA diagonal, so the
// diagonal's bf16 rounding error cancels: loss_i = ln2*(log2(T'_i) - s2'_i).
__global__ void __launch_bounds__(256) normalize_kernel(const float* __restrict__ in,
                                                        bf16* __restrict__ out,
                                                        float* __restrict__ Tg,
                                                        float* __restrict__ Dg,
                                                        float* __restrict__ loss_out) {
    if (blockIdx.x == 0 && threadIdx.x == 0) loss_out[0] = 0.0f;
    if (blockIdx.x < 64) Tg[blockIdx.x * 256 + threadIdx.x] = 0.0f;

    const int row  = blockIdx.x * 4 + (threadIdx.x >> 6);
    const int lane = threadIdx.x & 63;
    const float4* rp = (const float4*)(in + (size_t)row * DIM);
    float4 v = rp[lane];
    float ss = v.x * v.x + v.y * v.y + v.z * v.z + v.w * v.w;
#pragma unroll
    for (int m = 1; m < 64; m <<= 1) ss += __shfl_xor(ss, m, 64);
    float inv = SQK1 / fmaxf(sqrtf(ss), 1e-12f);
    bf16x4 o;
    o[0] = (bf16)(v.x * inv);
    o[1] = (bf16)(v.y * inv);
    o[2] = (bf16)(v.z * inv);
    o[3] = (bf16)(v.w * inv);
    *(bf16x4*)(out + (size_t)row * DIM + lane * 4) = o;

    float f0 = (float)o[0], f1 = (float)o[1], f2 = (float)o[2], f3 = (float)o[3];
    float s2 = f0 * f0 + f1 * f1 + f2 * f2 + f3 * f3;
#pragma unroll
    for (int m = 1; m < 64; m <<= 1) s2 += __shfl_xor(s2, m, 64);
    if (lane == 0) Dg[row] = s2;
}

// Tree-reduce 16 floats across the 32 `lo` lanes; every lane ends with the
// full sum for register index r = (lo>>1)&15. (Correctness-proven R4-R10.)
#define TREE16(R, out)                                                     \
    do {                                                                   \
        float w8[8], w4[4], w2[2], w1, g_;                                 \
        _Pragma("unroll") for (int i_ = 0; i_ < 8; ++i_) {                 \
            g_ = (lo & 16) ? R[i_] : R[i_ + 8];                            \
            w8[i_] = ((lo & 16) ? R[i_ + 8] : R[i_]) + __shfl_xor(g_, 16); \
        }                                                                  \
        _Pragma("unroll") for (int i_ = 0; i_ < 4; ++i_) {                 \
            g_ = (lo & 8) ? w8[i_] : w8[i_ + 4];                           \
            w4[i_] = ((lo & 8) ? w8[i_ + 4] : w8[i_]) + __shfl_xor(g_, 8); \
        }                                                                  \
        _Pragma("unroll") for (int i_ = 0; i_ < 2; ++i_) {                 \
            g_ = (lo & 4) ? w4[i_] : w4[i_ + 2];                           \
            w2[i_] = ((lo & 4) ? w4[i_ + 2] : w4[i_]) + __shfl_xor(g_, 4); \
        }                                                                  \
        g_ = (lo & 2) ? w2[0] : w2[1];                                     \
        w1 = ((lo & 2) ? w2[1] : w2[0]) + __shfl_xor(g_, 2);               \
        out = w1 + __shfl_xor(w1, 1);                                      \
    } while (0)

// Kernel 2: symmetric A'A'^T + softmax denominator.
// 512 thr = 8 waves = 4 row-groups(32 rows) x 2 col-groups(32 cols) per
// 128x64 tile. KEY CHANGE vs R10: 32-row waves halve per-wave register
// state (af[16]=64 + acc 16 + s0 16 ~= 115 regs total incl. AGPR) ->
// 4 waves/SIMD (R10's 64-row waves held 128 VGPR + 128 AGPR = 2/SIMD cap;
// occupancy, not delivery, was the binding constraint: exp2 epilogue
// (~66k cyc/CU, quarter-rate) equals the MFMA floor and must overlap it
// across waves). LDS = 2x32 KB dbuf + 8 KB CsAcc = 72 KB -> 2 blocks/CU
// -> 16 waves/CU. Pipeline: raw s_barrier + s_waitcnt vmcnt(4).
__global__ void __launch_bounds__(512, 4)
loss_kernel(const bf16* __restrict__ A, float* __restrict__ Tg) {
    __shared__ bf16 Bs0[64 * DIM];          // 32 KB
    __shared__ bf16 Bs1[64 * DIM];          // 32 KB
    __shared__ float CsAcc[4][LSTRIP][64];  // 8 KB

    const int tid = threadIdx.x;
    const int w  = tid >> 6;
    const int l  = tid & 63;
    const int lo = l & 31, hi = l >> 5;
    const int rg = w >> 1;   // row-group: rows rg*32..+31 (of the 128-row tile)
    const int cg = w & 1;    // col-group: cols cg*32..+31 (of the 64-col tile)

    // strip decode: (it, chunk of up to 8 col-tiles starting at jc0 >= 2*it)
    int it = 0, rem = blockIdx.x;
    for (;;) {
        int nch = (NJC - 2 * it + LSTRIP - 1) >> 3;
        if (rem < nch) break;
        rem -= nch;
        ++it;
    }
    const int jc0 = 2 * it + rem * LSTRIP;
    const int jc1 = (jc0 + LSTRIP < NJC) ? (jc0 + LSTRIP) : NJC;

    // persistent A fragments for the wave's 32 rows (A-op: m=lo, k=hi*8+j)
    bf16x8 af[16];
    {
        const bf16* ap = A + (size_t)(it * 128 + rg * 32 + lo) * DIM + hi * 8;
#pragma unroll
        for (int k = 0; k < 16; ++k)
            af[k] = *(const volatile bf16x8*)(ap + k * 16);
    }

    float s0[16];
#pragma unroll
    for (int r = 0; r < 16; ++r) s0[r] = 0.f;

    // DMA lane constants. Wave w stages B-tile rows w*8..+7 in 4 instrs
    // (2 rows each). Lane: rl = l>>5 (row in pair), s = l&31 (LDS slot).
    // Slot s of row r holds global chunk c = (s&24)|((s&7)^(r&7)).
    const int s_dma = l & 31;
    const int rl    = l >> 5;
    int vo[4];
#pragma unroll
    for (int q = 0; q < 4; ++q) {
        const int c = (s_dma & 24) | ((s_dma & 7) ^ ((q * 2 + rl) & 7));
        vo[q] = rl * DIM + c * 8;
    }

    // fragment-read constants: B row = cg*32+lo; chunk cc at slot
    // (cc&24)|((cc&7)^(lo&7))
    const int rbase = (cg * 32 + lo) * DIM;
    const int mx7 = lo & 7;

#define ISSUE(jcn, BUF)                                                      \
    do {                                                                     \
        const bf16* tb_ = A + (size_t)((jcn) * 64 + w * 8) * DIM;            \
        bf16* lb_ = &BUF[(w * 8) * DIM];                                     \
        _Pragma("unroll") for (int q_ = 0; q_ < 4; ++q_) {                   \
            GLOAD_LDS(tb_ + (q_ * 2) * DIM + vo[q_],                         \
                      lb_ + (q_ * 2) * DIM);                                 \
        }                                                                    \
    } while (0)

#define TILE_BODY(BR, BW, jc, t)                                             \
    do {                                                                     \
        asm volatile("s_barrier" ::: "memory");                              \
        if ((jc) + 1 < jc1) {                                                \
            ISSUE((jc) + 1, BW);                                             \
            asm volatile("s_waitcnt vmcnt(4)" ::: "memory");                 \
        } else {                                                             \
            asm volatile("s_waitcnt vmcnt(0)" ::: "memory");                 \
        }                                                                    \
        asm volatile("s_barrier" ::: "memory");                              \
        f32x16 c0;                                                           \
        _Pragma("unroll") for (int r_ = 0; r_ < 16; ++r_) c0[r_] = 0.f;      \
        _Pragma("unroll") for (int k_ = 0; k_ < 16; ++k_) {                  \
            const int cc_ = k_ * 2 + hi;                                     \
            const int slot_ = (cc_ & 24) | ((cc_ & 7) ^ mx7);                \
            bf16x8 b_ = *(const bf16x8*)&BR[rbase + slot_ * 8];              \
            c0 = __builtin_amdgcn_mfma_f32_32x32x16_bf16(af[k_], b_, c0, 0, 0, 0); \
        }                                                                    \
        float cs_ = 0.f;                                                     \
        _Pragma("unroll") for (int r_ = 0; r_ < 16; ++r_) {                  \
            float e_ = __builtin_amdgcn_exp2f(c0[r_]);                       \
            s0[r_] += e_;                                                    \
            cs_ += e_;                                                       \
        }                                                                    \
        cs_ += __shfl_xor(cs_, 32);                                          \
        if (hi == 0) CsAcc[rg][t][cg * 32 + lo] = cs_;                       \
    } while (0)

    ISSUE(jc0, Bs0);
    int jc = jc0;
    while (jc < jc1) {
        TILE_BODY(Bs0, Bs1, jc, jc - jc0);
        ++jc;
        if (jc >= jc1) break;
        TILE_BODY(Bs1, Bs0, jc, jc - jc0);
        ++jc;
    }

    // strip end: row sums. C/D row = (r&3)+8*(r>>2)+4*hi; even `lo` lanes
    // hold the tree result for r=(lo>>1).
    float t0;
    TREE16(s0, t0);
    const int r = (lo >> 1) & 15;
    const int rowoff = (r & 3) + 8 * (r >> 2) + 4 * hi;
    if ((l & 1) == 0)
        atomicAdd(&Tg[it * 128 + rg * 32 + rowoff], t0);

    // col-sum flush (skip the diagonal 128x128 block: jc>>1 == it — its
    // entries are fully covered by row sums).
    __syncthreads();
    const int nt_strip = jc1 - jc0;
    for (int i = tid; i < nt_strip * 64; i += 512) {
        const int t = i >> 6, col = i & 63;
        if (((jc0 + t) >> 1) != it) {
            atomicAdd(&Tg[(jc0 + t) * 64 + col],
                      CsAcc[0][t][col] + CsAcc[1][t][col] +
                      CsAcc[2][t][col] + CsAcc[3][t][col]);
        }
    }
#undef ISSUE
#undef TILE_BODY
}

// Kernel 3: loss_i = ln2*(log2(T'_i) - s2'_i), mean over rows.
__global__ void __launch_bounds__(256) final_kernel(const float* __restrict__ Tg,
                                                    const float* __restrict__ Dg,
                                                    float* __restrict__ out) {
    __shared__ float red[4];
    const int i = blockIdx.x * 256 + threadIdx.x;
    float c = LN2F * (__log2f(Tg[i]) - Dg[i]) * (1.0f / (float)N_ROWS);
#pragma unroll
    for (int m = 1; m < 64; m <<= 1) c += __shfl_xor(c, m, 64);
    if ((threadIdx.x & 63) == 0) red[threadIdx.x >> 6] = c;
    __syncthreads();
    if (threadIdx.x == 0)
        atomicAdd(out, red[0] + red[1] + red[2] + red[3]);
}

extern "C" void kernel_launch(void* const* d_in, const int* in_sizes, int n_in,
                              void* d_out, int out_size, void* d_ws, size_t ws_size,
                              hipStream_t stream) {
    const float* emb = (const float*)d_in[0];
    float* out = (float*)d_out;
    bf16* Abf = (bf16*)d_ws;
    float* Tg = (float*)((char*)d_ws + WS_T_OFF);
    float* Dg = (float*)((char*)d_ws + WS_D_OFF);

    hipLaunchKernelGGL(normalize_kernel, dim3(N_ROWS / 4), dim3(256), 0, stream,
                       emb, Abf, Tg, Dg, out);
    hipLaunchKernelGGL(loss_kernel, dim3(NSTRIPS), dim3(512), 0, stream,
                       Abf, Tg);
    hipLaunchKernelGGL(final_kernel, dim3(N_ROWS / 256), dim3(256), 0, stream,
                       Tg, Dg, out);
}